// Round 5
// baseline (187.403 us; speedup 1.0000x reference)
//
#include <hip/hip_runtime.h>

#define BB 4
#define NN 2048
#define DD 4
#define QQ (NN / 4)            // 512 quads along j
#define BLOCK 256
#define CHQ 64                 // quads per chunk per row (64 lanes x 1 quad)
#define NCHUNK (QQ / CHQ)      // 8 chunks

typedef float f4 __attribute__((ext_vector_type(4)));
typedef _Float16 h8 __attribute__((ext_vector_type(8)));
typedef _Float16 h2 __attribute__((ext_vector_type(2)));

#define GLOAD_LDS16(gp, lp)                                                      \
    __builtin_amdgcn_global_load_lds(                                            \
        (const __attribute__((address_space(1))) void*)(gp),                     \
        (__attribute__((address_space(3))) void*)(lp), 16, 0, 0)

// ---------------- precompute: sincos(theta) -> fp32 arrays (epilogue) + fp16 quad-packed table
// scT layout: [b][d][q] -> 8 halves {s(j0),c(j0),...,s(j3),c(j3)}, j = 4q+u
__global__ __launch_bounds__(BLOCK) void precomp(const float* __restrict__ theta,
                                                 float* __restrict__ sArr,
                                                 float* __restrict__ cArr,
                                                 h8* __restrict__ scT) {
    const int t = blockIdx.x * BLOCK + threadIdx.x;     // [0, B*QQ) = 2048
    const int b = t / QQ, q = t % QQ;
    const f4* theta4 = (const f4*)theta;
    f4* s4 = (f4*)sArr;
    f4* c4 = (f4*)cArr;

    float s[4][4], c[4][4];                              // [u][d]
    #pragma unroll
    for (int u = 0; u < 4; ++u) {
        const f4 th = theta4[(size_t)b * NN + 4 * q + u];
        #pragma unroll
        for (int d = 0; d < 4; ++d) __sincosf(th[d], &s[u][d], &c[u][d]);
    }
    #pragma unroll
    for (int u = 0; u < 4; ++u) {
        f4 sv, cv;
        #pragma unroll
        for (int d = 0; d < 4; ++d) { sv[d] = s[u][d]; cv[d] = c[u][d]; }
        s4[(size_t)b * NN + 4 * q + u] = sv;
        c4[(size_t)b * NN + 4 * q + u] = cv;
    }
    #pragma unroll
    for (int d = 0; d < 4; ++d) {
        h8 w;
        #pragma unroll
        for (int u = 0; u < 4; ++u) {
            w[2 * u]     = (_Float16)s[u][d];
            w[2 * u + 1] = (_Float16)c[u][d];
        }
        scT[((size_t)b * 4 + d) * QQ + q] = w;
    }
}

// ---------------- main: 2048 blocks, 4 waves/block, ONE row per wave.
// aff/alpha DMA'd into per-wave LDS slices via global_load_lds (async, deep MLP,
// no VGPR cost). NO barriers in the chunk loop: each wave only touches its own
// slice, pipelined on its own vmcnt.
__global__ __launch_bounds__(BLOCK, 4) void kuramoto_main(
    const float* __restrict__ theta,
    const float* __restrict__ gam,
    const float* __restrict__ aff,
    const float* __restrict__ alp,
    const float* __restrict__ omega,
    const float* __restrict__ kappa,
    const float* __restrict__ bias,
    const float* __restrict__ sArr,
    const float* __restrict__ cArr,
    const h8* __restrict__ scT,
    float* __restrict__ out)
{
    // XCD swizzle: batch-siblings (same rows, b=0..3) within a 32-block window
    // land on the same XCD close in time -> bias/scT L2 reuse.
    const int x   = blockIdx.x;                          // [0, 2048)
    const int low = x & 31;
    const int b   = low >> 3;
    const int g   = (x >> 5) * 8 + (low & 7);            // row-group [0, 512)
    const int i0  = g * 4;

    const int tid  = threadIdx.x;
    const int wave = tid >> 6;
    const int lane = tid & 63;
    const int i    = i0 + wave;                          // this wave's row

    __shared__ h8 lsc[4 * QQ];                           // 32 KB sincos table
    __shared__ f4 bufA[2][4 * CHQ];                      // 2 x 4 KB aff chunks
    __shared__ f4 bufL[2][4 * CHQ];                      // 2 x 4 KB alpha chunks

    const h8* gsc  = scT + (size_t)b * 4 * QQ;
    const f4* arow = (const f4*)(aff + (size_t)b * NN * NN) + (size_t)i * QQ;
    const f4* lrow = (const f4*)(alp + (size_t)b * NN * NN) + (size_t)i * QQ;
    const f4* brow = (const f4*)bias + (size_t)i * QQ;

    // ---- stage sc table via async DMA (wave-uniform dest + lane*16) ----
    #pragma unroll
    for (int k = 0; k < (4 * QQ) / BLOCK; ++k) {
        const int o = k * BLOCK + wave * 64;
        GLOAD_LDS16(gsc + o + lane, &lsc[o]);
    }
    // ---- issue chunk 0 for this wave's row ----
    GLOAD_LDS16(arow + lane, &bufA[0][wave * CHQ]);
    GLOAD_LDS16(lrow + lane, &bufL[0][wave * CHQ]);
    f4 bv_cur = brow[lane];                              // bias chunk 0 (regs)

    __syncthreads();                                     // sc table is cross-wave; one drain

    f4 accU = {0.f, 0.f, 0.f, 0.f};
    f4 accV = {0.f, 0.f, 0.f, 0.f};

    #pragma unroll
    for (int c = 0; c < NCHUNK; ++c) {
        const int cur = c & 1;
        f4 bv_nxt;
        if (c + 1 < NCHUNK) {
            const int qn = (c + 1) * CHQ + lane;
            GLOAD_LDS16(arow + qn, &bufA[cur ^ 1][wave * CHQ]);
            GLOAD_LDS16(lrow + qn, &bufL[cur ^ 1][wave * CHQ]);
            bv_nxt = brow[qn];
        }

        const int q = c * CHQ + lane;                    // this lane's quad
        const f4 af  = bufA[cur][wave * CHQ + lane];     // waits own vmcnt only
        const f4 al  = bufL[cur][wave * CHQ + lane];
        const f4 alr = al + bv_cur;

        h8 scd[4];
        #pragma unroll
        for (int d = 0; d < 4; ++d) scd[d] = lsc[d * QQ + q];

        #pragma unroll
        for (int u = 0; u < 4; ++u) {
            float sa, ca;
            __sincosf(alr[u], &sa, &ca);
            const float wc = af[u] * ca;
            const float ws = af[u] * sa;
            h2 hA, hB;
            hA[0] = (_Float16)wc; hA[1] = (_Float16)(-ws);
            hB[0] = (_Float16)ws; hB[1] = (_Float16)wc;
            #pragma unroll
            for (int d = 0; d < 4; ++d) {
                h2 p;
                p[0] = scd[d][2 * u];
                p[1] = scd[d][2 * u + 1];
#if __has_builtin(__builtin_amdgcn_fdot2)
                accU[d] = __builtin_amdgcn_fdot2(hA, p, accU[d], false);
                accV[d] = __builtin_amdgcn_fdot2(hB, p, accV[d], false);
#else
                accU[d] = fmaf(wc, (float)p[0], fmaf(-ws, (float)p[1], accU[d]));
                accV[d] = fmaf(ws, (float)p[0], fmaf( wc, (float)p[1], accV[d]));
#endif
            }
        }
        bv_cur = bv_nxt;
    }

    // ---- wave-local shuffle reduction; no barrier ----
    #pragma unroll
    for (int off = 32; off >= 1; off >>= 1) {
        #pragma unroll
        for (int d = 0; d < 4; ++d) {
            accU[d] += __shfl_down(accU[d], off, 64);
            accV[d] += __shfl_down(accV[d], off, 64);
        }
    }

    if (lane == 0) {
        const f4* theta4 = (const f4*)theta;
        const f4* gam4   = (const f4*)gam;
        const f4* om4    = (const f4*)omega;
        const f4* kp4    = (const f4*)kappa;
        const f4* s4     = (const f4*)sArr;
        const f4* c4     = (const f4*)cArr;
        f4* out4         = (f4*)out;

        const size_t base = (size_t)b * NN + i;
        const f4 th = theta4[base];
        const f4 gm = gam4[base];
        const f4 om = om4[i];
        const f4 kp = kp4[i];
        const f4 si = s4[base];
        const f4 ci = c4[base];
        f4 o;
        #pragma unroll
        for (int d = 0; d < 4; ++d) {
            const float coup = (1.0f / (float)NN) * (ci[d] * accU[d] - si[d] * accV[d]);
            o[d] = th[d] + om[d] + kp[d] * (gm[d] - th[d]) + coup;
        }
        out4[base] = o;
    }
}

extern "C" void kernel_launch(void* const* d_in, const int* in_sizes, int n_in,
                              void* d_out, int out_size, void* d_ws, size_t ws_size,
                              hipStream_t stream) {
    const float* theta = (const float*)d_in[0];
    const float* gam   = (const float*)d_in[1];
    const float* aff   = (const float*)d_in[2];
    const float* alp   = (const float*)d_in[3];
    const float* omega = (const float*)d_in[4];
    const float* kappa = (const float*)d_in[5];
    const float* bias  = (const float*)d_in[6];
    float* out  = (float*)d_out;

    float* sArr = (float*)d_ws;                          // [B*N*D] fp32
    float* cArr = sArr + BB * NN * DD;                   // [B*N*D] fp32
    h8*    scT  = (h8*)(cArr + BB * NN * DD);            // [B][4][QQ] fp16 pairs, 128 KB

    precomp<<<(BB * QQ) / BLOCK, BLOCK, 0, stream>>>(theta, sArr, cArr, scT);
    kuramoto_main<<<BB * (NN / 4), BLOCK, 0, stream>>>(
        theta, gam, aff, alp, omega, kappa, bias, sArr, cArr, scT, out);
}

// Round 7
// 172.420 us; speedup vs baseline: 1.0869x; 1.0869x over previous
//
#include <hip/hip_runtime.h>

#define BB 4
#define NN 2048
#define DD 4
#define QQ (NN / 4)          // 512 quads along j
#define BLOCK 256
#define JIT (QQ / 64)        // 8 j-iterations per lane

typedef float f4 __attribute__((ext_vector_type(4)));
typedef _Float16 h8 __attribute__((ext_vector_type(8)));
typedef _Float16 h2 __attribute__((ext_vector_type(2)));

// ---------------- precompute: sincos(theta) -> fp32 arrays (epilogue) + fp16 quad-packed planes
// scT layout: [b][d][q] -> 8 halves {s(j0),c(j0),s(j1),c(j1),s(j2),c(j2),s(j3),c(j3)}, j=4q+u
// One d-plane is 8 KB; per-batch table is 32 KB == L1 size.
__global__ __launch_bounds__(BLOCK) void precomp(const float* __restrict__ theta,
                                                 float* __restrict__ sArr,
                                                 float* __restrict__ cArr,
                                                 h8* __restrict__ scT) {
    const int t = blockIdx.x * BLOCK + threadIdx.x;     // [0, B*QQ) = 2048
    const int b = t / QQ, q = t % QQ;
    const f4* theta4 = (const f4*)theta;
    f4* s4 = (f4*)sArr;
    f4* c4 = (f4*)cArr;

    float s[4][4], c[4][4];                              // [u][d]
    #pragma unroll
    for (int u = 0; u < 4; ++u) {
        const f4 th = theta4[(size_t)b * NN + 4 * q + u];
        #pragma unroll
        for (int d = 0; d < 4; ++d) __sincosf(th[d], &s[u][d], &c[u][d]);
    }
    #pragma unroll
    for (int u = 0; u < 4; ++u) {
        f4 sv, cv;
        #pragma unroll
        for (int d = 0; d < 4; ++d) { sv[d] = s[u][d]; cv[d] = c[u][d]; }
        s4[(size_t)b * NN + 4 * q + u] = sv;
        c4[(size_t)b * NN + 4 * q + u] = cv;
    }
    #pragma unroll
    for (int d = 0; d < 4; ++d) {
        h8 w;
        #pragma unroll
        for (int u = 0; u < 4; ++u) {
            w[2 * u]     = (_Float16)s[u][d];
            w[2 * u + 1] = (_Float16)c[u][d];
        }
        scT[((size_t)b * 4 + d) * QQ + q] = w;
    }
}

// ---------------- main: 2048 blocks (b-major), 4 waves/block, ONE row per wave.
// No LDS. aff/alpha: nontemporal VGPR streams, depth-2 ring prefetch.
// sc: fp16 planes, normal loads -> L1-resident (32 KB/batch; b-major dispatch keeps
// co-resident blocks on one batch). Inner math: pkrtz + v_dot2_f32_f16.
__global__ __launch_bounds__(BLOCK, 5) void kuramoto_main(
    const float* __restrict__ theta,
    const float* __restrict__ gam,
    const float* __restrict__ aff,
    const float* __restrict__ alp,
    const float* __restrict__ omega,
    const float* __restrict__ kappa,
    const float* __restrict__ bias,
    const float* __restrict__ sArr,
    const float* __restrict__ cArr,
    const h8* __restrict__ scT,
    float* __restrict__ out)
{
    const int x = blockIdx.x;                            // [0, 2048), b-major
    const int b = x >> 9;
    const int g = x & 511;

    const int tid  = threadIdx.x;
    const int wave = tid >> 6;
    const int lane = tid & 63;
    const int i    = g * 4 + wave;                       // this wave's row

    const f4* arow = (const f4*)(aff + (size_t)b * NN * NN) + (size_t)i * QQ;
    const f4* lrow = (const f4*)(alp + (size_t)b * NN * NN) + (size_t)i * QQ;
    const f4* brow = (const f4*)bias + (size_t)i * QQ;
    const h8* scp  = scT + (size_t)b * 4 * QQ;           // 4 planes of QQ

    f4 accU = {0.f, 0.f, 0.f, 0.f};
    f4 accV = {0.f, 0.f, 0.f, 0.f};

    // depth-2 ring on aff/alpha; depth-1 on bias/sc
    f4 av[3], lv[3];
    f4 bv[2];
    h8 sc[2][4];

    av[0] = __builtin_nontemporal_load(&arow[lane]);
    lv[0] = __builtin_nontemporal_load(&lrow[lane]);
    av[1] = __builtin_nontemporal_load(&arow[lane + 64]);
    lv[1] = __builtin_nontemporal_load(&lrow[lane + 64]);
    bv[0] = brow[lane];
    #pragma unroll
    for (int d = 0; d < 4; ++d) sc[0][d] = scp[d * QQ + lane];

    #pragma unroll
    for (int jj = 0; jj < JIT; ++jj) {
        const int cur = jj & 1;
        const int nxt = cur ^ 1;
        const int s0  = jj % 3;

        if (jj + 2 < JIT) {
            const int qn = lane + 64 * (jj + 2);
            av[(jj + 2) % 3] = __builtin_nontemporal_load(&arow[qn]);
            lv[(jj + 2) % 3] = __builtin_nontemporal_load(&lrow[qn]);
        }
        if (jj + 1 < JIT) {
            const int qn = lane + 64 * (jj + 1);
            bv[nxt] = brow[qn];
            #pragma unroll
            for (int d = 0; d < 4; ++d) sc[nxt][d] = scp[d * QQ + qn];
        }

        const f4 af  = av[s0];
        const f4 alr = lv[s0] + bv[cur];

        #pragma unroll
        for (int u = 0; u < 4; ++u) {
            float sa, ca;
            __sincosf(alr[u], &sa, &ca);
            const float wc = af[u] * ca;
            const float ws = af[u] * sa;
#if __has_builtin(__builtin_amdgcn_cvt_pkrtz) && __has_builtin(__builtin_amdgcn_fdot2)
            const h2 hA = __builtin_bit_cast(h2, __builtin_amdgcn_cvt_pkrtz(wc, -ws));
            const h2 hB = __builtin_bit_cast(h2, __builtin_amdgcn_cvt_pkrtz(ws, wc));
            #pragma unroll
            for (int d = 0; d < 4; ++d) {
                h2 p;
                p[0] = sc[cur][d][2 * u];                // (s,c) pair == one VGPR of the h8
                p[1] = sc[cur][d][2 * u + 1];
                accU[d] = __builtin_amdgcn_fdot2(hA, p, accU[d], false);
                accV[d] = __builtin_amdgcn_fdot2(hB, p, accV[d], false);
            }
#else
            #pragma unroll
            for (int d = 0; d < 4; ++d) {
                const float sj = (float)sc[cur][d][2 * u];
                const float cj = (float)sc[cur][d][2 * u + 1];
                accU[d] = fmaf(wc, sj, fmaf(-ws, cj, accU[d]));
                accV[d] = fmaf(wc, cj, fmaf(ws, sj, accV[d]));
            }
#endif
        }
    }

    // ---- wave-local shuffle reduction; no barrier ----
    #pragma unroll
    for (int off = 32; off >= 1; off >>= 1) {
        #pragma unroll
        for (int d = 0; d < 4; ++d) {
            accU[d] += __shfl_down(accU[d], off, 64);
            accV[d] += __shfl_down(accV[d], off, 64);
        }
    }

    if (lane == 0) {
        const f4* theta4 = (const f4*)theta;
        const f4* gam4   = (const f4*)gam;
        const f4* om4    = (const f4*)omega;
        const f4* kp4    = (const f4*)kappa;
        const f4* s4     = (const f4*)sArr;
        const f4* c4     = (const f4*)cArr;
        f4* out4         = (f4*)out;

        const size_t base = (size_t)b * NN + i;
        const f4 th = theta4[base];
        const f4 gm = gam4[base];
        const f4 om = om4[i];
        const f4 kp = kp4[i];
        const f4 si = s4[base];
        const f4 ci = c4[base];
        f4 o;
        #pragma unroll
        for (int d = 0; d < 4; ++d) {
            const float coup = (1.0f / (float)NN) * (ci[d] * accU[d] - si[d] * accV[d]);
            o[d] = th[d] + om[d] + kp[d] * (gm[d] - th[d]) + coup;
        }
        out4[base] = o;
    }
}

extern "C" void kernel_launch(void* const* d_in, const int* in_sizes, int n_in,
                              void* d_out, int out_size, void* d_ws, size_t ws_size,
                              hipStream_t stream) {
    const float* theta = (const float*)d_in[0];
    const float* gam   = (const float*)d_in[1];
    const float* aff   = (const float*)d_in[2];
    const float* alp   = (const float*)d_in[3];
    const float* omega = (const float*)d_in[4];
    const float* kappa = (const float*)d_in[5];
    const float* bias  = (const float*)d_in[6];
    float* out  = (float*)d_out;

    float* sArr = (float*)d_ws;                          // [B*N*D] fp32
    float* cArr = sArr + BB * NN * DD;                   // [B*N*D] fp32
    h8*    scT  = (h8*)(cArr + BB * NN * DD);            // [B][4][QQ] fp16 pairs, 128 KB

    precomp<<<(BB * QQ) / BLOCK, BLOCK, 0, stream>>>(theta, sArr, cArr, scT);
    kuramoto_main<<<BB * (NN / 4), BLOCK, 0, stream>>>(
        theta, gam, aff, alp, omega, kappa, bias, sArr, cArr, scT, out);
}